// Round 6
// baseline (51.648 us; speedup 1.0000x reference)
//
#include <hip/hip_runtime.h>

#define WORKERS 2048
#define TASKS   2048
#define ETYPE   16
#define ABIL    64

#define F4_PER_WORKER  8192               // 32768 floats per worker / 4
#define ITERS          32                 // 8192 f4 / 256 threads

typedef float f4 __attribute__((ext_vector_type(4)));

// ---------------------------------------------------------------------------
// One worker per block (2048 blocks x 256 threads). Every thread redundantly
// computes the worker's l1=log2(p1), l2=log2(p2) (block-uniform addresses ->
// broadcast-cached loads; ~64 FMA + 2 transcendentals, negligible), then
// streams 32 lane-contiguous float4 stores with per-iter tau loads (tau is
// L2-resident: 512 KiB working set).
//   P[w][t][e] = exp2( tau[t][e]*l1 + (1-tau[t][e])*l2 )
// Two-term exponent form keeps the p1->1 (l2=-inf) case producing exact 0.
// Regular stores through L2 (nt-store bypassed L2 write-combining and
// regressed 46->57 us in round 4). unroll 8 keeps 8 independent tau loads in
// flight without excessive VGPR.
// ---------------------------------------------------------------------------
__global__ void __launch_bounds__(256)
fused_kernel(const float* __restrict__ inputs,
             const float* __restrict__ W,
             const float* __restrict__ b,
             f4* __restrict__ out) {
    const int w = blockIdx.x;             // worker index, block-uniform

    // --- per-worker scalars (redundant per thread, block-uniform) ---
    const f4* row = reinterpret_cast<const f4*>(inputs + (size_t)w * ABIL);
    const f4* Wv  = reinterpret_cast<const f4*>(W);
    float acc = 0.0f;
#pragma unroll
    for (int k = 0; k < ABIL / 4; ++k) {
        f4 x  = row[k];
        f4 wv = Wv[k];
        acc = fmaf(x.x, wv.x, acc);
        acc = fmaf(x.y, wv.y, acc);
        acc = fmaf(x.z, wv.z, acc);
        acc = fmaf(x.w, wv.w, acc);
    }
    acc += b[0];
    const float LOG2E = 1.4426950408889634f;
    float e  = __builtin_amdgcn_exp2f(-acc * LOG2E);
    float p1 = 1.0f / (1.0f + e);
    float p2 = (1.0f - p1) * (1.0f / (ETYPE - 1));
    const float a = __builtin_amdgcn_logf(p1);   // v_log_f32 = log2
    const float c = __builtin_amdgcn_logf(p2);

    // --- stream 32 float4 outputs, lane-contiguous per instruction ---
    const int base = w * F4_PER_WORKER + (int)threadIdx.x;
#pragma unroll 8
    for (int it = 0; it < ITERS; ++it) {
        const int i    = base + it * 256;
        const int rem4 = i & (F4_PER_WORKER - 1);     // = it*256 + tid
        const int t    = rem4 >> 2;                   // task index
        const int e0   = (rem4 & 3) * 4;              // edge-type offset
        const f4 tau = *reinterpret_cast<const f4*>(
            inputs + (size_t)(WORKERS + t) * ABIL + e0);   // L2-resident
        f4 r;
        r.x = __builtin_amdgcn_exp2f(fmaf(tau.x, a, (1.0f - tau.x) * c));
        r.y = __builtin_amdgcn_exp2f(fmaf(tau.y, a, (1.0f - tau.y) * c));
        r.z = __builtin_amdgcn_exp2f(fmaf(tau.z, a, (1.0f - tau.z) * c));
        r.w = __builtin_amdgcn_exp2f(fmaf(tau.w, a, (1.0f - tau.w) * c));
        out[i] = r;
    }
}

extern "C" void kernel_launch(void* const* d_in, const int* in_sizes, int n_in,
                              void* d_out, int out_size, void* d_ws, size_t ws_size,
                              hipStream_t stream) {
    const float* inputs = (const float*)d_in[0];
    const float* W      = (const float*)d_in[1];
    const float* b      = (const float*)d_in[2];

    fused_kernel<<<WORKERS, 256, 0, stream>>>(inputs, W, b, (f4*)d_out);
}

// Round 7
// 46.139 us; speedup vs baseline: 1.1194x; 1.1194x over previous
//
#include <hip/hip_runtime.h>

#define WORKERS 2048
#define TASKS   2048
#define ETYPE   16
#define ABIL    64

#define F4_PER_WORKER  8192               // 32768 floats per worker / 4
#define F4_PER_BLOCK   4096               // half a worker per block
#define ITERS          16                 // 4096 f4 / 256 threads

// ---------------------------------------------------------------------------
// Measured optimum (round 2, 46.3 us): half-worker per block, 4096 blocks,
// FULL unroll-16 so the compiler hoists all 16 independent tau loads and
// keeps 16 stores in flight per wave. One-worker/unroll-8 (51.6), LDS-fed
// store-only (47.6), and nontemporal stores (57.4) all regressed.
//   P[w][t][e] = exp2( tau[t][e]*l1 + (1-tau[t][e])*l2 )
// Two-term exponent form keeps the p1->1 (l2=-inf) case producing exact 0.
// ---------------------------------------------------------------------------
__global__ void __launch_bounds__(256)
fused_kernel(const float* __restrict__ inputs,
             const float* __restrict__ W,
             const float* __restrict__ b,
             float4* __restrict__ out) {
    const int blk  = blockIdx.x;
    const int w    = blk >> 1;            // worker index, block-uniform
    const int half = blk & 1;

    // --- per-worker scalars (redundant per thread, block-uniform) ---
    const float4* row = reinterpret_cast<const float4*>(inputs + (size_t)w * ABIL);
    const float4* Wv  = reinterpret_cast<const float4*>(W);
    float acc = 0.0f;
#pragma unroll
    for (int k = 0; k < ABIL / 4; ++k) {
        float4 x  = row[k];
        float4 wv = Wv[k];
        acc = fmaf(x.x, wv.x, acc);
        acc = fmaf(x.y, wv.y, acc);
        acc = fmaf(x.z, wv.z, acc);
        acc = fmaf(x.w, wv.w, acc);
    }
    acc += b[0];
    const float LOG2E = 1.4426950408889634f;
    float e  = __builtin_amdgcn_exp2f(-acc * LOG2E);
    float p1 = 1.0f / (1.0f + e);
    float p2 = (1.0f - p1) * (1.0f / (ETYPE - 1));
    const float a = __builtin_amdgcn_logf(p1);   // v_log_f32 = log2
    const float c = __builtin_amdgcn_logf(p2);

    // --- stream 16 float4 outputs, lane-contiguous per instruction ---
    const int base = w * F4_PER_WORKER + half * F4_PER_BLOCK + (int)threadIdx.x;
#pragma unroll
    for (int it = 0; it < ITERS; ++it) {
        const int i    = base + it * 256;
        const int rem4 = i & (F4_PER_WORKER - 1);     // f4 index within worker
        const int t    = rem4 >> 2;                   // task index
        const int e0   = (rem4 & 3) * 4;              // edge-type offset
        const float4 tau = *reinterpret_cast<const float4*>(
            inputs + (size_t)(WORKERS + t) * ABIL + e0);   // L2-resident
        float4 r;
        r.x = __builtin_amdgcn_exp2f(fmaf(tau.x, a, (1.0f - tau.x) * c));
        r.y = __builtin_amdgcn_exp2f(fmaf(tau.y, a, (1.0f - tau.y) * c));
        r.z = __builtin_amdgcn_exp2f(fmaf(tau.z, a, (1.0f - tau.z) * c));
        r.w = __builtin_amdgcn_exp2f(fmaf(tau.w, a, (1.0f - tau.w) * c));
        out[i] = r;
    }
}

extern "C" void kernel_launch(void* const* d_in, const int* in_sizes, int n_in,
                              void* d_out, int out_size, void* d_ws, size_t ws_size,
                              hipStream_t stream) {
    const float* inputs = (const float*)d_in[0];
    const float* W      = (const float*)d_in[1];
    const float* b      = (const float*)d_in[2];

    const int blocks = WORKERS * 2;       // 4096 blocks x 256 threads
    fused_kernel<<<blocks, 256, 0, stream>>>(inputs, W, b, (float4*)d_out);
}